// Round 6
// baseline (312.683 us; speedup 1.0000x reference)
//
#include <hip/hip_runtime.h>
#include <hip/hip_bf16.h>

#define D 128

typedef short short8 __attribute__((ext_vector_type(8)));
typedef float f32x4  __attribute__((ext_vector_type(4)));

__device__ __forceinline__ float lo_bf(unsigned u) { return __uint_as_float(u << 16); }
__device__ __forceinline__ float hi_bf(unsigned u) { return __uint_as_float(u & 0xFFFF0000u); }

// ---------------- Stage 1: in-degrees (2 edges/thread) ----------------
__global__ void deg_kernel(const int* __restrict__ dst, int* __restrict__ degs, int E) {
    int i = blockIdx.x * blockDim.x + threadIdx.x;
    int E2 = E >> 1;
    if (i < E2) {
        int2 d = ((const int2*)dst)[i];
        atomicAdd(&degs[d.x], 1);
        atomicAdd(&degs[d.y], 1);
    }
    if (i == 0 && (E & 1)) atomicAdd(&degs[dst[E - 1]], 1);
}

// ---------------- Stage 2: single-dispatch coalesced scan + norm ----------------
__global__ __launch_bounds__(1024) void scan_kernel(
    const int* __restrict__ degs, int* __restrict__ off, int* __restrict__ cursor,
    float* __restrict__ norm, int N, int E)
{
    __shared__ int wsum[16];
    __shared__ int carry_s;
    const int tid = threadIdx.x;
    const int lane = tid & 63, w = tid >> 6;
    if (tid == 0) carry_s = 0;
    __syncthreads();

    for (int base = 0; base < N; base += 1024) {
        int i = base + tid;
        int d = (i < N) ? degs[i] : 0;
        if (i < N) norm[i] = rsqrtf((float)d + 1.0f);

        int v = d;                                  // wave inclusive scan
        #pragma unroll
        for (int o = 1; o < 64; o <<= 1) {
            int t = __shfl_up(v, o, 64);
            if (lane >= o) v += t;
        }
        if (lane == 63) wsum[w] = v;
        __syncthreads();
        int woff = 0;
        #pragma unroll
        for (int k = 0; k < 16; ++k) woff += (k < w) ? wsum[k] : 0;

        int excl = carry_s + woff + v - d;
        if (i < N) { off[i] = excl; cursor[i] = excl; }
        __syncthreads();                            // all reads of carry_s done
        if (tid == 1023) carry_s += woff + v;       // tile total
        __syncthreads();
    }
    if (tid == 0) off[N] = E;
}

// ---------------- Stage 3: fill CSR (packed src | et<<20), 2 edges/thread ----------------
__global__ void fill_kernel(const int* __restrict__ src, const int* __restrict__ dst,
                            const int* __restrict__ efeat, int* __restrict__ cursor,
                            unsigned* __restrict__ csr, int E) {
    int i = blockIdx.x * blockDim.x + threadIdx.x;
    int E2 = E >> 1;
    if (i < E2) {
        int2 d = ((const int2*)dst)[i];
        int2 s = ((const int2*)src)[i];
        int2 t = ((const int2*)efeat)[i];
        int p0 = atomicAdd(&cursor[d.x], 1);
        csr[p0] = (unsigned)s.x | ((unsigned)t.x << 20);
        int p1 = atomicAdd(&cursor[d.y], 1);
        csr[p1] = (unsigned)s.y | ((unsigned)t.y << 20);
    }
    if (i == 0 && (E & 1)) {
        int p = atomicAdd(&cursor[dst[E - 1]], 1);
        csr[p] = (unsigned)src[E - 1] | ((unsigned)efeat[E - 1] << 20);
    }
}

// ---------------- Stage 4a: split W (f32) into truncated-bf16 hi/lo planes ----------------
__global__ void wsplit_kernel(const float* __restrict__ W, short* __restrict__ whi,
                              short* __restrict__ wlo) {
    int i = blockIdx.x * blockDim.x + threadIdx.x;
    if (i >= D * D) return;
    float w = W[i];
    unsigned u = __float_as_uint(w);
    float hi = __uint_as_float(u & 0xFFFF0000u);
    float lo = w - hi;
    whi[i] = (short)(u >> 16);
    wlo[i] = (short)(__float_as_uint(lo) >> 16);
}

// ---------------- Stage 4b: h = x @ W^T + b via split-bf16 MFMA (f32-accurate) ----------------
__global__ __launch_bounds__(256) void h_mfma_kernel(
    const float* __restrict__ x, const short* __restrict__ whi, const short* __restrict__ wlo,
    const float* __restrict__ b, __hip_bfloat16* __restrict__ hbf, int N)
{
    const int lane = threadIdx.x & 63;
    const int wave = threadIdx.x >> 6;
    const int m0 = (blockIdx.x * 4 + wave) * 16;
    if (m0 >= N) return;
    const int row  = lane & 15;
    const int quad = lane >> 4;
    int mrow = m0 + row; if (mrow >= N) mrow = N - 1;   // safe dup for ragged tail

    f32x4 acc[8];
    #pragma unroll
    for (int t = 0; t < 8; ++t) acc[t] = (f32x4){0.f, 0.f, 0.f, 0.f};

    #pragma unroll
    for (int kk = 0; kk < 4; ++kk) {
        const int ko = kk * 32 + quad * 8;
        const float4* xp4 = (const float4*)(x + (size_t)mrow * D + ko);
        float4 xa = xp4[0], xb = xp4[1];
        float xv[8] = {xa.x, xa.y, xa.z, xa.w, xb.x, xb.y, xb.z, xb.w};
        short8 ahi, alo;
        #pragma unroll
        for (int j = 0; j < 8; ++j) {
            unsigned u = __float_as_uint(xv[j]);
            float hi = __uint_as_float(u & 0xFFFF0000u);
            float lo = xv[j] - hi;
            ahi[j] = (short)(u >> 16);
            alo[j] = (short)(__float_as_uint(lo) >> 16);
        }
        #pragma unroll
        for (int t = 0; t < 8; ++t) {
            const short8 bhi = *(const short8*)(whi + (size_t)(t * 16 + row) * D + ko);
            const short8 blo = *(const short8*)(wlo + (size_t)(t * 16 + row) * D + ko);
            acc[t] = __builtin_amdgcn_mfma_f32_16x16x32_bf16(ahi, bhi, acc[t], 0, 0, 0);
            acc[t] = __builtin_amdgcn_mfma_f32_16x16x32_bf16(ahi, blo, acc[t], 0, 0, 0);
            acc[t] = __builtin_amdgcn_mfma_f32_16x16x32_bf16(alo, bhi, acc[t], 0, 0, 0);
        }
    }

    #pragma unroll
    for (int t = 0; t < 8; ++t) {
        const int col = t * 16 + row;
        const float bias = b[col];
        #pragma unroll
        for (int r = 0; r < 4; ++r) {
            const int m = m0 + quad * 4 + r;
            if (m < N) hbf[(size_t)m * D + col] = __float2bfloat16(acc[t][r] + bias);
        }
    }
}

// ---------------- Stage 5: gather-aggregate, 4 edges in flight per wave ----------------
// Group g = lane>>4 handles one edge; sublane s = lane&15 covers channels 8s..8s+7
// via one uint4 (16 B) load of the bf16 h-row. ee staged in LDS (pitch 132 words,
// ~2-way aliasing = free). Cross-group reduce via shfl_xor(16,32); fused residual.
#define EEP 132
__global__ __launch_bounds__(256) void agg_kernel(
    const int* __restrict__ off, const unsigned* __restrict__ csr,
    const float* __restrict__ norm, const uint4* __restrict__ hbf4,
    const float* __restrict__ ee, const float* __restrict__ res_w,
    float* __restrict__ out, int N)
{
    __shared__ float ees[16 * EEP];
    const int tid = threadIdx.x;
    for (int i = tid; i < 16 * 128; i += 256) {
        int et = i >> 7, c = i & 127;
        ees[et * EEP + c] = ee[i];
    }
    __syncthreads();

    const int n = blockIdx.x * 4 + (tid >> 6);
    if (n >= N) return;
    const int lane = tid & 63;
    const int g = lane >> 4;
    const int s = lane & 15;

    const int beg = off[n], end = off[n + 1];
    const int deg = end - beg;
    const float nd = norm[n];

    float acc[8];
    #pragma unroll
    for (int j = 0; j < 8; ++j) acc[j] = 0.f;

    for (int base = beg; base < end; base += 64) {
        int idx = base + lane;
        unsigned se = 0; float en = 0.f;
        if (idx < end) {
            se = csr[idx];
            en = norm[se & 0xFFFFF] * nd;
        }
        int cnt = end - base; if (cnt > 64) cnt = 64;
        #pragma unroll 4
        for (int j4 = 0; j4 < cnt; j4 += 4) {
            int sl = j4 + g;                          // per-lane src lane (ds_bpermute)
            unsigned sej = (unsigned)__shfl((int)se, sl);
            float enj = __shfl(en, sl);               // lanes >= cnt carry en=0
            int sj  = sej & 0xFFFFF;
            int etj = sej >> 20;
            uint4 hw = hbf4[(size_t)sj * 16 + s];
            const float* eep = ees + etj * EEP + 8 * s;
            float4 e0 = *(const float4*)(eep);
            float4 e1 = *(const float4*)(eep + 4);
            acc[0] = fmaf(fmaxf(lo_bf(hw.x) + e0.x, 0.f), enj, acc[0]);
            acc[1] = fmaf(fmaxf(hi_bf(hw.x) + e0.y, 0.f), enj, acc[1]);
            acc[2] = fmaf(fmaxf(lo_bf(hw.y) + e0.z, 0.f), enj, acc[2]);
            acc[3] = fmaf(fmaxf(hi_bf(hw.y) + e0.w, 0.f), enj, acc[3]);
            acc[4] = fmaf(fmaxf(lo_bf(hw.z) + e1.x, 0.f), enj, acc[4]);
            acc[5] = fmaf(fmaxf(hi_bf(hw.z) + e1.y, 0.f), enj, acc[5]);
            acc[6] = fmaf(fmaxf(lo_bf(hw.w) + e1.z, 0.f), enj, acc[6]);
            acc[7] = fmaf(fmaxf(hi_bf(hw.w) + e1.w, 0.f), enj, acc[7]);
        }
    }

    // reduce partial sums across the 4 groups
    #pragma unroll
    for (int j = 0; j < 8; ++j) {
        acc[j] += __shfl_xor(acc[j], 16, 64);
        acc[j] += __shfl_xor(acc[j], 32, 64);
    }

    if (g == 0) {
        uint4 hn = hbf4[(size_t)n * 16 + s];
        float invd = 1.0f / (float)(deg + 1);
        const float4* rwp = (const float4*)(res_w + 8 * s);
        float4 r0 = rwp[0], r1 = rwp[1];
        float4 o0, o1;
        o0.x = acc[0] + fmaxf(lo_bf(hn.x) + r0.x, 0.f) * invd;
        o0.y = acc[1] + fmaxf(hi_bf(hn.x) + r0.y, 0.f) * invd;
        o0.z = acc[2] + fmaxf(lo_bf(hn.y) + r0.z, 0.f) * invd;
        o0.w = acc[3] + fmaxf(hi_bf(hn.y) + r0.w, 0.f) * invd;
        o1.x = acc[4] + fmaxf(lo_bf(hn.z) + r1.x, 0.f) * invd;
        o1.y = acc[5] + fmaxf(hi_bf(hn.z) + r1.y, 0.f) * invd;
        o1.z = acc[6] + fmaxf(lo_bf(hn.w) + r1.z, 0.f) * invd;
        o1.w = acc[7] + fmaxf(hi_bf(hn.w) + r1.w, 0.f) * invd;
        float4* op = (float4*)(out + (size_t)n * D + 8 * s);
        op[0] = o0;
        op[1] = o1;
    }
}

extern "C" void kernel_launch(void* const* d_in, const int* in_sizes, int n_in,
                              void* d_out, int out_size, void* d_ws, size_t ws_size,
                              hipStream_t stream) {
    const float* nfeat = (const float*)d_in[0];
    const int* efeat   = (const int*)d_in[1];
    const int* src     = (const int*)d_in[2];
    const int* dst     = (const int*)d_in[3];
    const float* W     = (const float*)d_in[4];
    const float* b     = (const float*)d_in[5];
    const float* ee    = (const float*)d_in[6];
    const float* res_w = (const float*)d_in[7];

    const int N = in_sizes[0] / D;
    const int E = in_sizes[2];

    // workspace: degs | off | cursor | norm | csr | whi | wlo | hbf
    char* p = (char*)d_ws;
    int* degs      = (int*)p;      p += (size_t)N * 4;
    int* off       = (int*)p;      p += (size_t)(N + 1) * 4;
    int* cursor    = (int*)p;      p += (size_t)N * 4;
    float* norm    = (float*)p;    p += (size_t)N * 4;
    p = (char*)(((uintptr_t)p + 15) & ~(uintptr_t)15);
    unsigned* csr  = (unsigned*)p; p += (size_t)E * 4;
    p = (char*)(((uintptr_t)p + 15) & ~(uintptr_t)15);
    short* whi     = (short*)p;    p += (size_t)D * D * 2;
    short* wlo     = (short*)p;    p += (size_t)D * D * 2;
    p = (char*)(((uintptr_t)p + 15) & ~(uintptr_t)15);
    __hip_bfloat16* hbf = (__hip_bfloat16*)p;

    hipMemsetAsync(degs, 0, (size_t)N * 4, stream);

    const int E2 = (E + 1) >> 1;
    deg_kernel<<<(E2 + 255) / 256, 256, 0, stream>>>(dst, degs, E);
    wsplit_kernel<<<(D * D + 255) / 256, 256, 0, stream>>>(W, whi, wlo);
    scan_kernel<<<1, 1024, 0, stream>>>(degs, off, cursor, norm, N, E);
    fill_kernel<<<(E2 + 255) / 256, 256, 0, stream>>>(src, dst, efeat, cursor, csr, E);

    const int mtiles = (N + 15) / 16;
    h_mfma_kernel<<<(mtiles + 3) / 4, 256, 0, stream>>>(nfeat, whi, wlo, b, hbf, N);
    agg_kernel<<<(N + 3) / 4, 256, 0, stream>>>(off, csr, norm, (const uint4*)hbf,
                                                ee, res_w, (float*)d_out, N);
}

// Round 7
// 274.394 us; speedup vs baseline: 1.1395x; 1.1395x over previous
//
#include <hip/hip_runtime.h>
#include <hip/hip_bf16.h>

#define D 128

typedef short short8 __attribute__((ext_vector_type(8)));
typedef float f32x4  __attribute__((ext_vector_type(4)));

__device__ __forceinline__ float lo_bf(unsigned u) { return __uint_as_float(u << 16); }
__device__ __forceinline__ float hi_bf(unsigned u) { return __uint_as_float(u & 0xFFFF0000u); }

// ---------------- Stage 1: in-degrees (2 edges/thread) ----------------
__global__ void deg_kernel(const int* __restrict__ dst, int* __restrict__ degs, int E) {
    int i = blockIdx.x * blockDim.x + threadIdx.x;
    int E2 = E >> 1;
    if (i < E2) {
        int2 d = ((const int2*)dst)[i];
        atomicAdd(&degs[d.x], 1);
        atomicAdd(&degs[d.y], 1);
    }
    if (i == 0 && (E & 1)) atomicAdd(&degs[dst[E - 1]], 1);
}

// ---------------- Stage 2a: per-block degree sums + norm (196 blocks) ----------------
__global__ __launch_bounds__(256) void scan_blocks(
    const int* __restrict__ degs, int* __restrict__ blocksum,
    float* __restrict__ norm, int N)
{
    const int tid = threadIdx.x;
    const int i = blockIdx.x * 256 + tid;
    int d = (i < N) ? degs[i] : 0;
    if (i < N) norm[i] = rsqrtf((float)d + 1.0f);

    int v = d;
    #pragma unroll
    for (int o = 32; o > 0; o >>= 1) v += __shfl_down(v, o, 64);
    __shared__ int ws[4];
    if ((tid & 63) == 0) ws[tid >> 6] = v;
    __syncthreads();
    if (tid == 0) blocksum[blockIdx.x] = ws[0] + ws[1] + ws[2] + ws[3];
}

// ---------------- Stage 2b: scan block sums (nb <= 256) ----------------
__global__ __launch_bounds__(256) void scan_top(
    const int* __restrict__ blocksum, int* __restrict__ blockoff, int nb)
{
    __shared__ int s[256];
    const int tid = threadIdx.x;
    s[tid] = (tid < nb) ? blocksum[tid] : 0;
    __syncthreads();
    for (int o = 1; o < 256; o <<= 1) {
        int v = (tid >= o) ? s[tid - o] : 0;
        __syncthreads();
        s[tid] += v;
        __syncthreads();
    }
    if (tid < nb) blockoff[tid] = s[tid] - blocksum[tid];   // exclusive
}

// ---------------- Stage 2c: final offsets ----------------
__global__ __launch_bounds__(256) void scan_final(
    const int* __restrict__ degs, const int* __restrict__ blockoff,
    int* __restrict__ off, int* __restrict__ cursor, int N, int E)
{
    const int tid = threadIdx.x;
    const int i = blockIdx.x * 256 + tid;
    const int lane = tid & 63, w = tid >> 6;
    int d = (i < N) ? degs[i] : 0;

    int v = d;                                   // wave inclusive scan
    #pragma unroll
    for (int o = 1; o < 64; o <<= 1) {
        int t = __shfl_up(v, o, 64);
        if (lane >= o) v += t;
    }
    __shared__ int ws[4];
    if (lane == 63) ws[w] = v;
    __syncthreads();
    int woff = 0;
    #pragma unroll
    for (int k = 0; k < 4; ++k) if (k < w) woff += ws[k];

    int excl = blockoff[blockIdx.x] + woff + v - d;
    if (i < N) { off[i] = excl; cursor[i] = excl; }
    if (blockIdx.x == 0 && tid == 0) off[N] = E;
}

// ---------------- Stage 3: fill CSR (packed src | et<<20), 2 edges/thread ----------------
__global__ void fill_kernel(const int* __restrict__ src, const int* __restrict__ dst,
                            const int* __restrict__ efeat, int* __restrict__ cursor,
                            unsigned* __restrict__ csr, int E) {
    int i = blockIdx.x * blockDim.x + threadIdx.x;
    int E2 = E >> 1;
    if (i < E2) {
        int2 d = ((const int2*)dst)[i];
        int2 s = ((const int2*)src)[i];
        int2 t = ((const int2*)efeat)[i];
        int p0 = atomicAdd(&cursor[d.x], 1);
        csr[p0] = (unsigned)s.x | ((unsigned)t.x << 20);
        int p1 = atomicAdd(&cursor[d.y], 1);
        csr[p1] = (unsigned)s.y | ((unsigned)t.y << 20);
    }
    if (i == 0 && (E & 1)) {
        int p = atomicAdd(&cursor[dst[E - 1]], 1);
        csr[p] = (unsigned)src[E - 1] | ((unsigned)efeat[E - 1] << 20);
    }
}

// ---------------- Stage 4a: split W (f32) into truncated-bf16 hi/lo planes ----------------
__global__ void wsplit_kernel(const float* __restrict__ W, short* __restrict__ whi,
                              short* __restrict__ wlo) {
    int i = blockIdx.x * blockDim.x + threadIdx.x;
    if (i >= D * D) return;
    float w = W[i];
    unsigned u = __float_as_uint(w);
    float hi = __uint_as_float(u & 0xFFFF0000u);
    float lo = w - hi;
    whi[i] = (short)(u >> 16);
    wlo[i] = (short)(__float_as_uint(lo) >> 16);
}

// ---------------- Stage 4b: h = x @ W^T + b via split-bf16 MFMA (f32-accurate) ----------------
__global__ __launch_bounds__(256) void h_mfma_kernel(
    const float* __restrict__ x, const short* __restrict__ whi, const short* __restrict__ wlo,
    const float* __restrict__ b, __hip_bfloat16* __restrict__ hbf, int N)
{
    const int lane = threadIdx.x & 63;
    const int wave = threadIdx.x >> 6;
    const int m0 = (blockIdx.x * 4 + wave) * 16;
    if (m0 >= N) return;
    const int row  = lane & 15;
    const int quad = lane >> 4;
    int mrow = m0 + row; if (mrow >= N) mrow = N - 1;   // safe dup for ragged tail

    f32x4 acc[8];
    #pragma unroll
    for (int t = 0; t < 8; ++t) acc[t] = (f32x4){0.f, 0.f, 0.f, 0.f};

    #pragma unroll
    for (int kk = 0; kk < 4; ++kk) {
        const int ko = kk * 32 + quad * 8;
        const float4* xp4 = (const float4*)(x + (size_t)mrow * D + ko);
        float4 xa = xp4[0], xb = xp4[1];
        float xv[8] = {xa.x, xa.y, xa.z, xa.w, xb.x, xb.y, xb.z, xb.w};
        short8 ahi, alo;
        #pragma unroll
        for (int j = 0; j < 8; ++j) {
            unsigned u = __float_as_uint(xv[j]);
            float hi = __uint_as_float(u & 0xFFFF0000u);
            float lo = xv[j] - hi;
            ahi[j] = (short)(u >> 16);
            alo[j] = (short)(__float_as_uint(lo) >> 16);
        }
        #pragma unroll
        for (int t = 0; t < 8; ++t) {
            const short8 bhi = *(const short8*)(whi + (size_t)(t * 16 + row) * D + ko);
            const short8 blo = *(const short8*)(wlo + (size_t)(t * 16 + row) * D + ko);
            acc[t] = __builtin_amdgcn_mfma_f32_16x16x32_bf16(ahi, bhi, acc[t], 0, 0, 0);
            acc[t] = __builtin_amdgcn_mfma_f32_16x16x32_bf16(ahi, blo, acc[t], 0, 0, 0);
            acc[t] = __builtin_amdgcn_mfma_f32_16x16x32_bf16(alo, bhi, acc[t], 0, 0, 0);
        }
    }

    #pragma unroll
    for (int t = 0; t < 8; ++t) {
        const int col = t * 16 + row;
        const float bias = b[col];
        #pragma unroll
        for (int r = 0; r < 4; ++r) {
            const int m = m0 + quad * 4 + r;
            if (m < N) hbf[(size_t)m * D + col] = __float2bfloat16(acc[t][r] + bias);
        }
    }
}

// ---------------- Stage 5: gather-aggregate, 4 edges in flight per wave ----------------
// Group g = lane>>4 handles one edge; sublane s = lane&15 covers channels 8s..8s+7
// via one uint4 (16 B) load of the bf16 h-row. ee staged in LDS (pitch 132 words,
// ~2-way aliasing = free). Cross-group reduce via shfl_xor(16,32); fused residual.
#define EEP 132
__global__ __launch_bounds__(256) void agg_kernel(
    const int* __restrict__ off, const unsigned* __restrict__ csr,
    const float* __restrict__ norm, const uint4* __restrict__ hbf4,
    const float* __restrict__ ee, const float* __restrict__ res_w,
    float* __restrict__ out, int N)
{
    __shared__ float ees[16 * EEP];
    const int tid = threadIdx.x;
    for (int i = tid; i < 16 * 128; i += 256) {
        int et = i >> 7, c = i & 127;
        ees[et * EEP + c] = ee[i];
    }
    __syncthreads();

    const int n = blockIdx.x * 4 + (tid >> 6);
    if (n >= N) return;
    const int lane = tid & 63;
    const int g = lane >> 4;
    const int s = lane & 15;

    const int beg = off[n], end = off[n + 1];
    const int deg = end - beg;
    const float nd = norm[n];

    float acc[8];
    #pragma unroll
    for (int j = 0; j < 8; ++j) acc[j] = 0.f;

    for (int base = beg; base < end; base += 64) {
        int idx = base + lane;
        unsigned se = 0; float en = 0.f;
        if (idx < end) {
            se = csr[idx];
            en = norm[se & 0xFFFFF] * nd;
        }
        int cnt = end - base; if (cnt > 64) cnt = 64;
        #pragma unroll 4
        for (int j4 = 0; j4 < cnt; j4 += 4) {
            int sl = j4 + g;                          // per-lane src lane (ds_bpermute)
            unsigned sej = (unsigned)__shfl((int)se, sl);
            float enj = __shfl(en, sl);               // lanes >= cnt carry en=0
            int sj  = sej & 0xFFFFF;
            int etj = sej >> 20;
            uint4 hw = hbf4[(size_t)sj * 16 + s];
            const float* eep = ees + etj * EEP + 8 * s;
            float4 e0 = *(const float4*)(eep);
            float4 e1 = *(const float4*)(eep + 4);
            acc[0] = fmaf(fmaxf(lo_bf(hw.x) + e0.x, 0.f), enj, acc[0]);
            acc[1] = fmaf(fmaxf(hi_bf(hw.x) + e0.y, 0.f), enj, acc[1]);
            acc[2] = fmaf(fmaxf(lo_bf(hw.y) + e0.z, 0.f), enj, acc[2]);
            acc[3] = fmaf(fmaxf(hi_bf(hw.y) + e0.w, 0.f), enj, acc[3]);
            acc[4] = fmaf(fmaxf(lo_bf(hw.z) + e1.x, 0.f), enj, acc[4]);
            acc[5] = fmaf(fmaxf(hi_bf(hw.z) + e1.y, 0.f), enj, acc[5]);
            acc[6] = fmaf(fmaxf(lo_bf(hw.w) + e1.z, 0.f), enj, acc[6]);
            acc[7] = fmaf(fmaxf(hi_bf(hw.w) + e1.w, 0.f), enj, acc[7]);
        }
    }

    // reduce partial sums across the 4 groups
    #pragma unroll
    for (int j = 0; j < 8; ++j) {
        acc[j] += __shfl_xor(acc[j], 16, 64);
        acc[j] += __shfl_xor(acc[j], 32, 64);
    }

    if (g == 0) {
        uint4 hn = hbf4[(size_t)n * 16 + s];
        float invd = 1.0f / (float)(deg + 1);
        const float4* rwp = (const float4*)(res_w + 8 * s);
        float4 r0 = rwp[0], r1 = rwp[1];
        float4 o0, o1;
        o0.x = acc[0] + fmaxf(lo_bf(hn.x) + r0.x, 0.f) * invd;
        o0.y = acc[1] + fmaxf(hi_bf(hn.x) + r0.y, 0.f) * invd;
        o0.z = acc[2] + fmaxf(lo_bf(hn.y) + r0.z, 0.f) * invd;
        o0.w = acc[3] + fmaxf(hi_bf(hn.y) + r0.w, 0.f) * invd;
        o1.x = acc[4] + fmaxf(lo_bf(hn.z) + r1.x, 0.f) * invd;
        o1.y = acc[5] + fmaxf(hi_bf(hn.z) + r1.y, 0.f) * invd;
        o1.z = acc[6] + fmaxf(lo_bf(hn.w) + r1.z, 0.f) * invd;
        o1.w = acc[7] + fmaxf(hi_bf(hn.w) + r1.w, 0.f) * invd;
        float4* op = (float4*)(out + (size_t)n * D + 8 * s);
        op[0] = o0;
        op[1] = o1;
    }
}

extern "C" void kernel_launch(void* const* d_in, const int* in_sizes, int n_in,
                              void* d_out, int out_size, void* d_ws, size_t ws_size,
                              hipStream_t stream) {
    const float* nfeat = (const float*)d_in[0];
    const int* efeat   = (const int*)d_in[1];
    const int* src     = (const int*)d_in[2];
    const int* dst     = (const int*)d_in[3];
    const float* W     = (const float*)d_in[4];
    const float* b     = (const float*)d_in[5];
    const float* ee    = (const float*)d_in[6];
    const float* res_w = (const float*)d_in[7];

    const int N = in_sizes[0] / D;
    const int E = in_sizes[2];
    const int nb = (N + 255) / 256;   // 196 <= 256

    // workspace: degs | off | cursor | norm | blocksum | blockoff | csr | whi | wlo | hbf
    char* p = (char*)d_ws;
    int* degs      = (int*)p;      p += (size_t)N * 4;
    int* off       = (int*)p;      p += (size_t)(N + 1) * 4;
    int* cursor    = (int*)p;      p += (size_t)N * 4;
    float* norm    = (float*)p;    p += (size_t)N * 4;
    int* blocksum  = (int*)p;      p += 256 * 4;
    int* blockoff  = (int*)p;      p += 256 * 4;
    p = (char*)(((uintptr_t)p + 15) & ~(uintptr_t)15);
    unsigned* csr  = (unsigned*)p; p += (size_t)E * 4;
    p = (char*)(((uintptr_t)p + 15) & ~(uintptr_t)15);
    short* whi     = (short*)p;    p += (size_t)D * D * 2;
    short* wlo     = (short*)p;    p += (size_t)D * D * 2;
    p = (char*)(((uintptr_t)p + 15) & ~(uintptr_t)15);
    __hip_bfloat16* hbf = (__hip_bfloat16*)p;

    hipMemsetAsync(degs, 0, (size_t)N * 4, stream);

    const int E2 = (E + 1) >> 1;
    deg_kernel<<<(E2 + 255) / 256, 256, 0, stream>>>(dst, degs, E);
    wsplit_kernel<<<(D * D + 255) / 256, 256, 0, stream>>>(W, whi, wlo);
    scan_blocks<<<nb, 256, 0, stream>>>(degs, blocksum, norm, N);
    scan_top<<<1, 256, 0, stream>>>(blocksum, blockoff, nb);
    scan_final<<<nb, 256, 0, stream>>>(degs, blockoff, off, cursor, N, E);
    fill_kernel<<<(E2 + 255) / 256, 256, 0, stream>>>(src, dst, efeat, cursor, csr, E);

    const int mtiles = (N + 15) / 16;
    h_mfma_kernel<<<(mtiles + 3) / 4, 256, 0, stream>>>(nfeat, whi, wlo, b, hbf, N);
    agg_kernel<<<(N + 3) / 4, 256, 0, stream>>>(off, csr, norm, (const uint4*)hbf,
                                                ee, res_w, (float*)d_out, N);
}

// Round 8
// 268.159 us; speedup vs baseline: 1.1660x; 1.0233x over previous
//
#include <hip/hip_runtime.h>
#include <hip/hip_bf16.h>

#define D 128

typedef short short8 __attribute__((ext_vector_type(8)));
typedef float f32x4  __attribute__((ext_vector_type(4)));

__device__ __forceinline__ float lo_bf(unsigned u) { return __uint_as_float(u << 16); }
__device__ __forceinline__ float hi_bf(unsigned u) { return __uint_as_float(u & 0xFFFF0000u); }

// ---------------- Stage 1: in-degrees (4 edges/thread, fire-and-forget) ----------------
__global__ void deg_kernel(const int* __restrict__ dst, int* __restrict__ degs, int E) {
    int i = blockIdx.x * blockDim.x + threadIdx.x;
    int E4 = E >> 2;
    if (i < E4) {
        int4 d = ((const int4*)dst)[i];
        atomicAdd(&degs[d.x], 1);
        atomicAdd(&degs[d.y], 1);
        atomicAdd(&degs[d.z], 1);
        atomicAdd(&degs[d.w], 1);
    }
    if (i < (E & 3)) atomicAdd(&degs[dst[(E & ~3) + i]], 1);
}

// ---------------- Stage 2a: per-block degree sums + norm ----------------
__global__ __launch_bounds__(256) void scan_blocks(
    const int* __restrict__ degs, int* __restrict__ blocksum,
    float* __restrict__ norm, int N)
{
    const int tid = threadIdx.x;
    const int i = blockIdx.x * 256 + tid;
    int d = (i < N) ? degs[i] : 0;
    if (i < N) norm[i] = rsqrtf((float)d + 1.0f);

    int v = d;
    #pragma unroll
    for (int o = 32; o > 0; o >>= 1) v += __shfl_down(v, o, 64);
    __shared__ int ws[4];
    if ((tid & 63) == 0) ws[tid >> 6] = v;
    __syncthreads();
    if (tid == 0) blocksum[blockIdx.x] = ws[0] + ws[1] + ws[2] + ws[3];
}

// ---------------- Stage 2b: scan block sums (nb <= 256) ----------------
__global__ __launch_bounds__(256) void scan_top(
    const int* __restrict__ blocksum, int* __restrict__ blockoff, int nb)
{
    __shared__ int s[256];
    const int tid = threadIdx.x;
    s[tid] = (tid < nb) ? blocksum[tid] : 0;
    __syncthreads();
    for (int o = 1; o < 256; o <<= 1) {
        int v = (tid >= o) ? s[tid - o] : 0;
        __syncthreads();
        s[tid] += v;
        __syncthreads();
    }
    if (tid < nb) blockoff[tid] = s[tid] - blocksum[tid];   // exclusive
}

// ---------------- Stage 2c: final offsets ----------------
__global__ __launch_bounds__(256) void scan_final(
    const int* __restrict__ degs, const int* __restrict__ blockoff,
    int* __restrict__ off, int* __restrict__ cursor, int N, int E)
{
    const int tid = threadIdx.x;
    const int i = blockIdx.x * 256 + tid;
    const int lane = tid & 63, w = tid >> 6;
    int d = (i < N) ? degs[i] : 0;

    int v = d;                                   // wave inclusive scan
    #pragma unroll
    for (int o = 1; o < 64; o <<= 1) {
        int t = __shfl_up(v, o, 64);
        if (lane >= o) v += t;
    }
    __shared__ int ws[4];
    if (lane == 63) ws[w] = v;
    __syncthreads();
    int woff = 0;
    #pragma unroll
    for (int k = 0; k < 4; ++k) if (k < w) woff += ws[k];

    int excl = blockoff[blockIdx.x] + woff + v - d;
    if (i < N) { off[i] = excl; cursor[i] = excl; }
    if (blockIdx.x == 0 && tid == 0) off[N] = E;
}

// ---------------- Stage 3: fill CSR (packed src | et<<20), 4 edges/thread ----------------
__global__ void fill_kernel(const int* __restrict__ src, const int* __restrict__ dst,
                            const int* __restrict__ efeat, int* __restrict__ cursor,
                            unsigned* __restrict__ csr, int E) {
    int i = blockIdx.x * blockDim.x + threadIdx.x;
    int E4 = E >> 2;
    if (i < E4) {
        int4 d = ((const int4*)dst)[i];
        int4 s = ((const int4*)src)[i];
        int4 t = ((const int4*)efeat)[i];
        int p0 = atomicAdd(&cursor[d.x], 1);
        int p1 = atomicAdd(&cursor[d.y], 1);
        int p2 = atomicAdd(&cursor[d.z], 1);
        int p3 = atomicAdd(&cursor[d.w], 1);
        csr[p0] = (unsigned)s.x | ((unsigned)t.x << 20);
        csr[p1] = (unsigned)s.y | ((unsigned)t.y << 20);
        csr[p2] = (unsigned)s.z | ((unsigned)t.z << 20);
        csr[p3] = (unsigned)s.w | ((unsigned)t.w << 20);
    }
    if (i < (E & 3)) {
        int e = (E & ~3) + i;
        int p = atomicAdd(&cursor[dst[e]], 1);
        csr[p] = (unsigned)src[e] | ((unsigned)efeat[e] << 20);
    }
}

// ---------------- Stage 4a: split W (f32) into truncated-bf16 hi/lo planes ----------------
__global__ void wsplit_kernel(const float* __restrict__ W, short* __restrict__ whi,
                              short* __restrict__ wlo) {
    int i = blockIdx.x * blockDim.x + threadIdx.x;
    if (i >= D * D) return;
    float w = W[i];
    unsigned u = __float_as_uint(w);
    float hi = __uint_as_float(u & 0xFFFF0000u);
    float lo = w - hi;
    whi[i] = (short)(u >> 16);
    wlo[i] = (short)(__float_as_uint(lo) >> 16);
}

// ---------------- Stage 4b: h = x @ W^T + b via split-bf16 MFMA (f32-accurate) ----------------
__global__ __launch_bounds__(256) void h_mfma_kernel(
    const float* __restrict__ x, const short* __restrict__ whi, const short* __restrict__ wlo,
    const float* __restrict__ b, __hip_bfloat16* __restrict__ hbf, int N)
{
    const int lane = threadIdx.x & 63;
    const int wave = threadIdx.x >> 6;
    const int m0 = (blockIdx.x * 4 + wave) * 16;
    if (m0 >= N) return;
    const int row  = lane & 15;
    const int quad = lane >> 4;
    int mrow = m0 + row; if (mrow >= N) mrow = N - 1;   // safe dup for ragged tail

    f32x4 acc[8];
    #pragma unroll
    for (int t = 0; t < 8; ++t) acc[t] = (f32x4){0.f, 0.f, 0.f, 0.f};

    #pragma unroll
    for (int kk = 0; kk < 4; ++kk) {
        const int ko = kk * 32 + quad * 8;
        const float4* xp4 = (const float4*)(x + (size_t)mrow * D + ko);
        float4 xa = xp4[0], xb = xp4[1];
        float xv[8] = {xa.x, xa.y, xa.z, xa.w, xb.x, xb.y, xb.z, xb.w};
        short8 ahi, alo;
        #pragma unroll
        for (int j = 0; j < 8; ++j) {
            unsigned u = __float_as_uint(xv[j]);
            float hi = __uint_as_float(u & 0xFFFF0000u);
            float lo = xv[j] - hi;
            ahi[j] = (short)(u >> 16);
            alo[j] = (short)(__float_as_uint(lo) >> 16);
        }
        #pragma unroll
        for (int t = 0; t < 8; ++t) {
            const short8 bhi = *(const short8*)(whi + (size_t)(t * 16 + row) * D + ko);
            const short8 blo = *(const short8*)(wlo + (size_t)(t * 16 + row) * D + ko);
            acc[t] = __builtin_amdgcn_mfma_f32_16x16x32_bf16(ahi, bhi, acc[t], 0, 0, 0);
            acc[t] = __builtin_amdgcn_mfma_f32_16x16x32_bf16(ahi, blo, acc[t], 0, 0, 0);
            acc[t] = __builtin_amdgcn_mfma_f32_16x16x32_bf16(alo, bhi, acc[t], 0, 0, 0);
        }
    }

    #pragma unroll
    for (int t = 0; t < 8; ++t) {
        const int col = t * 16 + row;
        const float bias = b[col];
        #pragma unroll
        for (int r = 0; r < 4; ++r) {
            const int m = m0 + quad * 4 + r;
            if (m < N) hbf[(size_t)m * D + col] = __float2bfloat16(acc[t][r] + bias);
        }
    }
}

// ---------------- Stage 5: gather-aggregate, 8 edges in flight per wave ----------------
// Group g = lane>>3 handles one edge; sublane s = lane&7 covers channels
// {8s..8s+7} and {64+8s..64+8s+7} via two independent uint4 loads (2x MLP vs r6).
// ee staged in LDS (pitch 132). Cross-group reduce shfl_xor(8,16,32); fused residual.
#define EEP 132
__global__ __launch_bounds__(256) void agg_kernel(
    const int* __restrict__ off, const unsigned* __restrict__ csr,
    const float* __restrict__ norm, const uint4* __restrict__ hbf4,
    const float* __restrict__ ee, const float* __restrict__ res_w,
    float* __restrict__ out, int N)
{
    __shared__ float ees[16 * EEP];
    const int tid = threadIdx.x;
    for (int i = tid; i < 16 * 128; i += 256) {
        int et = i >> 7, c = i & 127;
        ees[et * EEP + c] = ee[i];
    }
    __syncthreads();

    const int n = blockIdx.x * 4 + (tid >> 6);
    if (n >= N) return;
    const int lane = tid & 63;
    const int g = lane >> 3;     // 8 edge-groups
    const int s = lane & 7;      // 8 sublanes

    const int beg = off[n], end = off[n + 1];
    const int deg = end - beg;
    const float nd = norm[n];

    float acc[16];
    #pragma unroll
    for (int j = 0; j < 16; ++j) acc[j] = 0.f;

    for (int base = beg; base < end; base += 64) {
        int idx = base + lane;
        unsigned se = 0; float en = 0.f;
        if (idx < end) {
            se = csr[idx];
            en = norm[se & 0xFFFFF] * nd;
        }
        int cnt = end - base; if (cnt > 64) cnt = 64;
        #pragma unroll 2
        for (int j8 = 0; j8 < cnt; j8 += 8) {
            int sl = j8 + g;
            unsigned sej = (unsigned)__shfl((int)se, sl);
            float enj = __shfl(en, sl);               // lanes >= cnt carry en=0
            int sj  = sej & 0xFFFFF;
            int etj = sej >> 20;
            uint4 h0 = hbf4[(size_t)sj * 16 + s];
            uint4 h1 = hbf4[(size_t)sj * 16 + s + 8];
            const float* ep = ees + etj * EEP + 8 * s;
            float4 ea = *(const float4*)(ep);
            float4 eb = *(const float4*)(ep + 4);
            float4 ec = *(const float4*)(ep + 64);
            float4 ed = *(const float4*)(ep + 68);
            acc[0]  = fmaf(fmaxf(lo_bf(h0.x) + ea.x, 0.f), enj, acc[0]);
            acc[1]  = fmaf(fmaxf(hi_bf(h0.x) + ea.y, 0.f), enj, acc[1]);
            acc[2]  = fmaf(fmaxf(lo_bf(h0.y) + ea.z, 0.f), enj, acc[2]);
            acc[3]  = fmaf(fmaxf(hi_bf(h0.y) + ea.w, 0.f), enj, acc[3]);
            acc[4]  = fmaf(fmaxf(lo_bf(h0.z) + eb.x, 0.f), enj, acc[4]);
            acc[5]  = fmaf(fmaxf(hi_bf(h0.z) + eb.y, 0.f), enj, acc[5]);
            acc[6]  = fmaf(fmaxf(lo_bf(h0.w) + eb.z, 0.f), enj, acc[6]);
            acc[7]  = fmaf(fmaxf(hi_bf(h0.w) + eb.w, 0.f), enj, acc[7]);
            acc[8]  = fmaf(fmaxf(lo_bf(h1.x) + ec.x, 0.f), enj, acc[8]);
            acc[9]  = fmaf(fmaxf(hi_bf(h1.x) + ec.y, 0.f), enj, acc[9]);
            acc[10] = fmaf(fmaxf(lo_bf(h1.y) + ec.z, 0.f), enj, acc[10]);
            acc[11] = fmaf(fmaxf(hi_bf(h1.y) + ec.w, 0.f), enj, acc[11]);
            acc[12] = fmaf(fmaxf(lo_bf(h1.z) + ed.x, 0.f), enj, acc[12]);
            acc[13] = fmaf(fmaxf(hi_bf(h1.z) + ed.y, 0.f), enj, acc[13]);
            acc[14] = fmaf(fmaxf(lo_bf(h1.w) + ed.z, 0.f), enj, acc[14]);
            acc[15] = fmaf(fmaxf(hi_bf(h1.w) + ed.w, 0.f), enj, acc[15]);
        }
    }

    // reduce partial sums across the 8 groups (same s)
    #pragma unroll
    for (int j = 0; j < 16; ++j) {
        acc[j] += __shfl_xor(acc[j], 8, 64);
        acc[j] += __shfl_xor(acc[j], 16, 64);
        acc[j] += __shfl_xor(acc[j], 32, 64);
    }

    if (g == 0) {   // lanes 0..7
        uint4 hn0 = hbf4[(size_t)n * 16 + s];
        uint4 hn1 = hbf4[(size_t)n * 16 + s + 8];
        float invd = 1.0f / (float)(deg + 1);
        const float4* rwp = (const float4*)(res_w + 8 * s);
        float4 r0 = rwp[0], r1 = rwp[1];
        const float4* rwq = (const float4*)(res_w + 64 + 8 * s);
        float4 r2 = rwq[0], r3 = rwq[1];
        float4 o0, o1, o2, o3;
        o0.x = acc[0]  + fmaxf(lo_bf(hn0.x) + r0.x, 0.f) * invd;
        o0.y = acc[1]  + fmaxf(hi_bf(hn0.x) + r0.y, 0.f) * invd;
        o0.z = acc[2]  + fmaxf(lo_bf(hn0.y) + r0.z, 0.f) * invd;
        o0.w = acc[3]  + fmaxf(hi_bf(hn0.y) + r0.w, 0.f) * invd;
        o1.x = acc[4]  + fmaxf(lo_bf(hn0.z) + r1.x, 0.f) * invd;
        o1.y = acc[5]  + fmaxf(hi_bf(hn0.z) + r1.y, 0.f) * invd;
        o1.z = acc[6]  + fmaxf(lo_bf(hn0.w) + r1.z, 0.f) * invd;
        o1.w = acc[7]  + fmaxf(hi_bf(hn0.w) + r1.w, 0.f) * invd;
        o2.x = acc[8]  + fmaxf(lo_bf(hn1.x) + r2.x, 0.f) * invd;
        o2.y = acc[9]  + fmaxf(hi_bf(hn1.x) + r2.y, 0.f) * invd;
        o2.z = acc[10] + fmaxf(lo_bf(hn1.y) + r2.z, 0.f) * invd;
        o2.w = acc[11] + fmaxf(hi_bf(hn1.y) + r2.w, 0.f) * invd;
        o3.x = acc[12] + fmaxf(lo_bf(hn1.z) + r3.x, 0.f) * invd;
        o3.y = acc[13] + fmaxf(hi_bf(hn1.z) + r3.y, 0.f) * invd;
        o3.z = acc[14] + fmaxf(lo_bf(hn1.w) + r3.z, 0.f) * invd;
        o3.w = acc[15] + fmaxf(hi_bf(hn1.w) + r3.w, 0.f) * invd;
        float4* op = (float4*)(out + (size_t)n * D + 8 * s);
        op[0] = o0;
        op[1] = o1;
        float4* oq = (float4*)(out + (size_t)n * D + 64 + 8 * s);
        oq[0] = o2;
        oq[1] = o3;
    }
}

extern "C" void kernel_launch(void* const* d_in, const int* in_sizes, int n_in,
                              void* d_out, int out_size, void* d_ws, size_t ws_size,
                              hipStream_t stream) {
    const float* nfeat = (const float*)d_in[0];
    const int* efeat   = (const int*)d_in[1];
    const int* src     = (const int*)d_in[2];
    const int* dst     = (const int*)d_in[3];
    const float* W     = (const float*)d_in[4];
    const float* b     = (const float*)d_in[5];
    const float* ee    = (const float*)d_in[6];
    const float* res_w = (const float*)d_in[7];

    const int N = in_sizes[0] / D;
    const int E = in_sizes[2];
    const int nb = (N + 255) / 256;   // 196 <= 256

    // workspace: degs | off | cursor | norm | blocksum | blockoff | csr | whi | wlo | hbf
    char* p = (char*)d_ws;
    int* degs      = (int*)p;      p += (size_t)N * 4;
    int* off       = (int*)p;      p += (size_t)(N + 1) * 4;
    int* cursor    = (int*)p;      p += (size_t)N * 4;
    float* norm    = (float*)p;    p += (size_t)N * 4;
    int* blocksum  = (int*)p;      p += 256 * 4;
    int* blockoff  = (int*)p;      p += 256 * 4;
    p = (char*)(((uintptr_t)p + 15) & ~(uintptr_t)15);
    unsigned* csr  = (unsigned*)p; p += (size_t)E * 4;
    p = (char*)(((uintptr_t)p + 15) & ~(uintptr_t)15);
    short* whi     = (short*)p;    p += (size_t)D * D * 2;
    short* wlo     = (short*)p;    p += (size_t)D * D * 2;
    p = (char*)(((uintptr_t)p + 15) & ~(uintptr_t)15);
    __hip_bfloat16* hbf = (__hip_bfloat16*)p;

    hipMemsetAsync(degs, 0, (size_t)N * 4, stream);

    const int E4 = (E + 3) >> 2;
    deg_kernel<<<(E4 + 255) / 256, 256, 0, stream>>>(dst, degs, E);
    wsplit_kernel<<<(D * D + 255) / 256, 256, 0, stream>>>(W, whi, wlo);
    scan_blocks<<<nb, 256, 0, stream>>>(degs, blocksum, norm, N);
    scan_top<<<1, 256, 0, stream>>>(blocksum, blockoff, nb);
    scan_final<<<nb, 256, 0, stream>>>(degs, blockoff, off, cursor, N, E);
    fill_kernel<<<(E4 + 255) / 256, 256, 0, stream>>>(src, dst, efeat, cursor, csr, E);

    const int mtiles = (N + 15) / 16;
    h_mfma_kernel<<<(mtiles + 3) / 4, 256, 0, stream>>>(nfeat, whi, wlo, b, hbf, N);
    agg_kernel<<<(N + 3) / 4, 256, 0, stream>>>(off, csr, norm, (const uint4*)hbf,
                                                ee, res_w, (float*)d_out, N);
}